// Round 1
// baseline (514.089 us; speedup 1.0000x reference)
//
#include <hip/hip_runtime.h>
#include <hip/hip_bf16.h>

#define B_DIM 64
#define T_DIM 2048
#define D_DIM 512
#define U_DIM 512

typedef __bf16 bf16x8 __attribute__((ext_vector_type(8)));
typedef float  f32x4  __attribute__((ext_vector_type(4)));
typedef unsigned int u32;

// ---------------------------------------------------------------------------
// W1 [D][U] fp32 -> w1s bf16 in K-plane layout: w1s[kb2][u][k], kb2=d>>5, k=d&31.
// offset = kb2*16384 + u*32 + k. Grid (16,8), block 256. LDS tile transpose.
// ---------------------------------------------------------------------------
__global__ void w1s_kernel(const float* __restrict__ W1w, __bf16* __restrict__ w1s) {
    __shared__ float tile[64][33];
    const int tid = threadIdx.x;
    const int kb2 = blockIdx.x;          // 32-d block
    const int ub  = blockIdx.y;          // 64-u block
    #pragma unroll
    for (int i = 0; i < 8; ++i) {
        int k = i * 4 + (tid >> 6);                 // 0..31
        int u = tid & 63;
        tile[u][k] = W1w[(kb2 * 32 + k) * U_DIM + ub * 64 + u];
    }
    __syncthreads();
    int u_l = tid >> 2;                  // 0..63
    int kp  = (tid & 3) * 8;             // 0,8,16,24
    bf16x8 w;
    #pragma unroll
    for (int j = 0; j < 8; ++j) w[j] = (__bf16)tile[u_l][kp + j];
    *reinterpret_cast<bf16x8*>(&w1s[kb2 * 16384 + (ub * 64 + u_l) * 32 + kp]) = w;
}

// ---------------------------------------------------------------------------
// hp[b][u] = W1_b[u] + W2_b[u] + hidden[b,:] @ W2[:,u]. Grid (B,2), block 256.
// ---------------------------------------------------------------------------
__global__ void hproj_kernel(const float* __restrict__ hidden,
                             const float* __restrict__ W2w,
                             const float* __restrict__ W2b,
                             const float* __restrict__ W1b,
                             float* __restrict__ hp) {
    int b = blockIdx.x;
    int u = blockIdx.y * 256 + threadIdx.x;
    float acc = W2b[u] + W1b[u];
    const float* hrow = hidden + b * D_DIM;
    #pragma unroll 8
    for (int d = 0; d < D_DIM; ++d)
        acc = fmaf(hrow[d], W2w[d * U_DIM + u], acc);
    hp[b * U_DIM + u] = acc;
}

// ---------------------------------------------------------------------------
// scores[row] = sum_{u<512} tanh(features[row,:]@W1[:,u] + hp[b,u]) * Vw[u]
// One block = 64 rows x ALL 512 u.
// NEW STRUCTURE: stage ALL of A (64 rows x 512 k -> 64 KiB bf16 LDS) with ONE
// barrier; B (w1s, 512 KiB, L2-resident) is read directly global->VGPR as
// coalesced 1 KiB wave segments, double-buffered one 32-k plane ahead.
// ZERO barriers / zero vmcnt(0) drains in the K loop.
// Grid 2048, block 256 (4 waves, each: 64 rows x 128 u). 2 blocks/CU.
// ---------------------------------------------------------------------------
__global__ __launch_bounds__(256, 2) void score_kernel(
        const float*  __restrict__ features,
        const __bf16* __restrict__ w1s,
        const float*  __restrict__ hp,
        const float*  __restrict__ Vw,
        float*        __restrict__ scores) {
    __shared__ __align__(16) __bf16 As[16 * 64 * 32];   // [kb][row][k], 64 KiB
    __shared__ float red[4 * 64];

    const int tid  = threadIdx.x;
    const int row0 = blockIdx.x * 64;          // flattened (b,t) base
    const int b    = row0 >> 11;

    const int wn   = tid >> 6;                 // wave 0..3 -> u window wn*128
    const int lane = tid & 63;
    const int l16  = lane & 15;
    const int quad = lane >> 4;

    f32x4 acc[4][8];
    #pragma unroll
    for (int i = 0; i < 4; ++i)
        #pragma unroll
        for (int j = 0; j < 8; ++j)
            acc[i][j] = (f32x4)0.0f;

    // ---- stage ALL of A: 64 rows x 512 k fp32 -> bf16 LDS, one barrier ----
    // thread: row = tid>>2, k-lane = tid&3. Per plane c: d = c*32 + aq*8..+7.
    // Per instruction, 4-lane groups cover full 128B lines (proven pattern).
    {
        const int arow = tid >> 2;
        const int aq   = tid & 3;
        const float* ag = features + (size_t)(row0 + arow) * D_DIM + aq * 8;
        __bf16* aw = As + arow * 32 + aq * 8;
        #pragma unroll
        for (int c = 0; c < 16; ++c) {
            const float4* s = reinterpret_cast<const float4*>(ag + c * 32);
            float4 v0 = s[0], v1 = s[1];
            bf16x8 w;
            w[0] = (__bf16)v0.x; w[1] = (__bf16)v0.y; w[2] = (__bf16)v0.z; w[3] = (__bf16)v0.w;
            w[4] = (__bf16)v1.x; w[5] = (__bf16)v1.y; w[6] = (__bf16)v1.z; w[7] = (__bf16)v1.w;
            *reinterpret_cast<bf16x8*>(aw + c * 2048) = w;
        }
    }

    // B fragment base: u = wn*128 + nt*16 + l16, k = quad*8 (+ nt*512 + kb*16384)
    const __bf16* bb = w1s + (wn * 128 + l16) * 32 + quad * 8;
    const __bf16* Ab = As + l16 * 32 + quad * 8;

    // preload plane 0 B while other waves finish staging (no LDS dependency)
    bf16x8 bA[8], bB[8];
    #pragma unroll
    for (int nt = 0; nt < 8; ++nt)
        bA[nt] = *reinterpret_cast<const bf16x8*>(bb + nt * 512);

    __syncthreads();

// One 32-k plane: prefetch plane KB+1 into BN, ds_read A, 32 MFMA with BC.
#define PLANE_STEP(KB, BC, BN, PF)                                           \
    {                                                                        \
        if (PF) {                                                            \
            _Pragma("unroll")                                                \
            for (int nt = 0; nt < 8; ++nt)                                   \
                BN[nt] = *reinterpret_cast<const bf16x8*>(                   \
                    bb + ((KB) + 1) * 16384 + nt * 512);                     \
        }                                                                    \
        bf16x8 af[4];                                                        \
        _Pragma("unroll")                                                    \
        for (int mt = 0; mt < 4; ++mt)                                       \
            af[mt] = *reinterpret_cast<const bf16x8*>(                       \
                Ab + (KB) * 2048 + mt * 512);                                \
        _Pragma("unroll")                                                    \
        for (int mt = 0; mt < 4; ++mt)                                       \
            _Pragma("unroll")                                                \
            for (int nt = 0; nt < 8; ++nt)                                   \
                acc[mt][nt] = __builtin_amdgcn_mfma_f32_16x16x32_bf16(       \
                    af[mt], BC[nt], acc[mt][nt], 0, 0, 0);                   \
    }

    #pragma unroll
    for (int k2 = 0; k2 < 8; ++k2) {
        PLANE_STEP(2 * k2,     bA, bB, 1);
        PLANE_STEP(2 * k2 + 1, bB, bA, ((2 * k2 + 1) < 15));
    }
#undef PLANE_STEP

    // ---- epilogue: tanh(f_proj + hp) . Vw, reduce over u ----
    float hpv[8], vwv[8];
    #pragma unroll
    for (int nt = 0; nt < 8; ++nt) {
        int u = wn * 128 + nt * 16 + l16;       // C/D col = lane&15
        hpv[nt] = hp[b * U_DIM + u];
        vwv[nt] = Vw[u];
    }
    #pragma unroll
    for (int mt = 0; mt < 4; ++mt) {
        #pragma unroll
        for (int reg = 0; reg < 4; ++reg) {
            float s = 0.0f;
            #pragma unroll
            for (int nt = 0; nt < 8; ++nt) {
                float x = acc[mt][nt][reg] + hpv[nt];
                float e = exp2f(x * 2.88539008f);           // e^{2x}
                float th = 1.0f - 2.0f * __builtin_amdgcn_rcpf(e + 1.0f);
                s = fmaf(th, vwv[nt], s);
            }
            s += __shfl_xor(s, 1);
            s += __shfl_xor(s, 2);
            s += __shfl_xor(s, 4);
            s += __shfl_xor(s, 8);
            if (l16 == 0)
                red[wn * 64 + mt * 16 + quad * 4 + reg] = s;  // C/D row = quad*4+reg
        }
    }
    __syncthreads();
    if (tid < 64)
        scores[row0 + tid] = red[tid] + red[64 + tid] + red[128 + tid] + red[192 + tid];
}

// ---------------------------------------------------------------------------
// softmax over T per batch. 64 blocks x 256 threads, 8 elems/thread.
// ---------------------------------------------------------------------------
__global__ void softmax_kernel(const float* __restrict__ scores, float* __restrict__ attn) {
    int b = blockIdx.x;
    int tid = threadIdx.x;
    __shared__ float red[4], red2[4];

    float s[8];
    float m = -1e30f;
    #pragma unroll
    for (int i = 0; i < 8; ++i) {
        s[i] = scores[b * T_DIM + i * 256 + tid];
        m = fmaxf(m, s[i]);
    }
    #pragma unroll
    for (int off = 1; off < 64; off <<= 1) m = fmaxf(m, __shfl_xor(m, off));
    if ((tid & 63) == 0) red[tid >> 6] = m;
    __syncthreads();
    m = fmaxf(fmaxf(red[0], red[1]), fmaxf(red[2], red[3]));

    float e[8], sum = 0.0f;
    #pragma unroll
    for (int i = 0; i < 8; ++i) {
        e[i] = exp2f((s[i] - m) * 1.44269504f);
        sum += e[i];
    }
    #pragma unroll
    for (int off = 1; off < 64; off <<= 1) sum += __shfl_xor(sum, off);
    if ((tid & 63) == 0) red2[tid >> 6] = sum;
    __syncthreads();
    sum = red2[0] + red2[1] + red2[2] + red2[3];
    float inv = 1.0f / sum;
    #pragma unroll
    for (int i = 0; i < 8; ++i)
        attn[b * T_DIM + i * 256 + tid] = e[i] * inv;
}

// ---------------------------------------------------------------------------
// context[b][d] = sum_t attn[b][t] * features[b][t][d]
// Grid (4, 64), block 256: block owns (b, 32 float4 columns) for ALL T.
// 8 t-partitions per thread-group -> LDS reduce -> direct store (no atomics).
// ---------------------------------------------------------------------------
__global__ void context_kernel(const float* __restrict__ attn,
                               const float* __restrict__ features,
                               float* __restrict__ out) {
    __shared__ float4 red[256];
    const int tid = threadIdx.x;
    const int b   = blockIdx.y;
    const int d4  = (blockIdx.x << 5) + (tid & 31);   // float4 column 0..127
    const int tp  = tid >> 5;                          // 0..7

    const float4* f  = reinterpret_cast<const float4*>(features) + (size_t)b * T_DIM * 128;
    const float*  ar = attn + b * T_DIM;

    float4 acc = {0.f, 0.f, 0.f, 0.f};
    #pragma unroll 8
    for (int i = 0; i < 256; ++i) {
        int t = tp * 256 + i;
        float a = ar[t];
        float4 v = f[(size_t)t * 128 + d4];
        acc.x = fmaf(a, v.x, acc.x);
        acc.y = fmaf(a, v.y, acc.y);
        acc.z = fmaf(a, v.z, acc.z);
        acc.w = fmaf(a, v.w, acc.w);
    }
    red[tid] = acc;
    __syncthreads();
    if (tp == 0) {
        float4 s = red[tid];
        #pragma unroll
        for (int j = 1; j < 8; ++j) {
            float4 v = red[tid + 32 * j];
            s.x += v.x; s.y += v.y; s.z += v.z; s.w += v.w;
        }
        reinterpret_cast<float4*>(out)[b * 128 + d4] = s;
    }
}

// ---------------------------------------------------------------------------
extern "C" void kernel_launch(void* const* d_in, const int* in_sizes, int n_in,
                              void* d_out, int out_size, void* d_ws, size_t ws_size,
                              hipStream_t stream) {
    const float* features = (const float*)d_in[0];
    const float* hidden   = (const float*)d_in[1];
    const float* W1w      = (const float*)d_in[2];
    const float* W1b      = (const float*)d_in[3];
    const float* W2w      = (const float*)d_in[4];
    const float* W2b      = (const float*)d_in[5];
    const float* Vw       = (const float*)d_in[6];
    // V_b cancels in softmax — unused.

    char* ws = (char*)d_ws;
    __bf16* w1s    = (__bf16*)ws;                      // 512 KiB
    float*  scores = (float*)(ws + (512u << 10));      // 512 KiB
    float*  attn   = (float*)(ws + (1024u << 10));     // 512 KiB
    float*  hp     = (float*)(ws + (1536u << 10));     // 128 KiB

    hipLaunchKernelGGL(w1s_kernel, dim3(16, 8), dim3(256), 0, stream, W1w, w1s);
    hipLaunchKernelGGL(hproj_kernel, dim3(B_DIM, 2), dim3(256), 0, stream,
                       hidden, W2w, W2b, W1b, hp);
    hipLaunchKernelGGL(score_kernel, dim3(2048), dim3(256), 0, stream,
                       features, w1s, hp, Vw, scores);
    hipLaunchKernelGGL(softmax_kernel, dim3(B_DIM), dim3(256), 0, stream, scores, attn);
    hipLaunchKernelGGL(context_kernel, dim3(4, B_DIM), dim3(256), 0, stream,
                       attn, features, (float*)d_out);
}

// Round 2
// 475.759 us; speedup vs baseline: 1.0806x; 1.0806x over previous
//
#include <hip/hip_runtime.h>
#include <hip/hip_bf16.h>

#define B_DIM 64
#define T_DIM 2048
#define D_DIM 512
#define U_DIM 512

typedef __bf16 bf16x8 __attribute__((ext_vector_type(8)));
typedef float  f32x4  __attribute__((ext_vector_type(4)));
typedef unsigned int u32;

// async global->LDS, 16B per lane (global_load_lds_dwordx4)
__device__ __forceinline__ void gl_lds16(const __bf16* g, __bf16* l) {
    __builtin_amdgcn_global_load_lds(
        (const __attribute__((address_space(1))) u32*)g,
        (__attribute__((address_space(3))) u32*)l,
        16, 0, 0);
}

// ---------------------------------------------------------------------------
// W1 [D][U] fp32 -> w1s bf16 in K-plane layout: w1s[kb2][u][k], kb2=d>>5, k=d&31.
// offset = kb2*16384 + u*32 + k. Grid (16,8), block 256. LDS tile transpose.
// ---------------------------------------------------------------------------
__global__ void w1s_kernel(const float* __restrict__ W1w, __bf16* __restrict__ w1s) {
    __shared__ float tile[64][33];
    const int tid = threadIdx.x;
    const int kb2 = blockIdx.x;          // 32-d block
    const int ub  = blockIdx.y;          // 64-u block
    #pragma unroll
    for (int i = 0; i < 8; ++i) {
        int k = i * 4 + (tid >> 6);                 // 0..31
        int u = tid & 63;
        tile[u][k] = W1w[(kb2 * 32 + k) * U_DIM + ub * 64 + u];
    }
    __syncthreads();
    int u_l = tid >> 2;                  // 0..63
    int kp  = (tid & 3) * 8;             // 0,8,16,24
    bf16x8 w;
    #pragma unroll
    for (int j = 0; j < 8; ++j) w[j] = (__bf16)tile[u_l][kp + j];
    *reinterpret_cast<bf16x8*>(&w1s[kb2 * 16384 + (ub * 64 + u_l) * 32 + kp]) = w;
}

// ---------------------------------------------------------------------------
// hp[b][u] = W1_b[u] + W2_b[u] + hidden[b,:] @ W2[:,u]. Grid (B,2), block 256.
// ---------------------------------------------------------------------------
__global__ void hproj_kernel(const float* __restrict__ hidden,
                             const float* __restrict__ W2w,
                             const float* __restrict__ W2b,
                             const float* __restrict__ W1b,
                             float* __restrict__ hp) {
    int b = blockIdx.x;
    int u = blockIdx.y * 256 + threadIdx.x;
    float acc = W2b[u] + W1b[u];
    const float* hrow = hidden + b * D_DIM;
    #pragma unroll 8
    for (int d = 0; d < D_DIM; ++d)
        acc = fmaf(hrow[d], W2w[d * U_DIM + u], acc);
    hp[b * U_DIM + u] = acc;
}

// ---------------------------------------------------------------------------
// FUSED: scores + chunk-local online softmax + unnormalized context partial.
// One block = 64 (b,t) rows. Phase A: GEMM tanh-score (2-phase pipelined LDS
// staging, BK=32, dbuf A+B). Phase B: chunk max/sum (m_c,l_c). Phase C:
// ctx_c[d] = sum_t e^{s_t-m_c} * features[t][d]  (rows are L2/L3-hot).
// Grid 2048, block 256 (4 waves x 128 u). LDS ~75 KiB -> 2 blocks/CU.
// ---------------------------------------------------------------------------
__global__ __launch_bounds__(256, 2) void score_ctx_kernel(
        const float*  __restrict__ features,
        const __bf16* __restrict__ w1s,
        const float*  __restrict__ hp,
        const float*  __restrict__ Vw,
        float*        __restrict__ ctx,     // [2048][512]
        float*        __restrict__ mv,      // [2048]
        float*        __restrict__ lv) {    // [2048]
    __shared__ __align__(16) char smem[8192 + 65536 + 1024 + 256];
    __bf16* As  = (__bf16*)smem;                      // [2][64*32]   8 KiB
    __bf16* Bs  = (__bf16*)(smem + 8192);             // [2][512*32] 64 KiB
    float*  red = (float*)(smem + 8192 + 65536);      // 256 f32      1 KiB
    float*  se  = (float*)(smem + 8192 + 65536 + 1024); // 64 f32
    float4* red4 = (float4*)Bs;                       // phase-C alias (4 KiB)

    const int tid  = threadIdx.x;
    const int chunk = blockIdx.x;
    const int row0 = chunk * 64;               // flattened (b,t) base
    const int b    = row0 >> 11;

    const int wn   = tid >> 6;                 // wave 0..3 -> u window wn*128
    const int lane = tid & 63;
    const int l16  = lane & 15;
    const int quad = lane >> 4;

    f32x4 acc[4][8];
    #pragma unroll
    for (int i = 0; i < 4; ++i)
        #pragma unroll
        for (int j = 0; j < 8; ++j)
            acc[i][j] = (f32x4)0.0f;

    // staging thread mapping: 4 threads/row, 128B fp32 per 4-lane group
    const int arow = tid >> 2;
    const int aq   = tid & 3;
    const float* agp = features + (size_t)(row0 + arow) * D_DIM + aq * 8;

    // ---- prologue: stage plane 0 into buffer 0 ----
    {
        const __bf16* src = w1s + tid * 8;
        #pragma unroll
        for (int c = 0; c < 8; ++c)
            gl_lds16(src + c * 2048, Bs + c * 2048 + tid * 8);
        const float4* s = reinterpret_cast<const float4*>(agp);
        float4 v0 = s[0], v1 = s[1];
        bf16x8 w;
        w[0] = (__bf16)v0.x; w[1] = (__bf16)v0.y; w[2] = (__bf16)v0.z; w[3] = (__bf16)v0.w;
        w[4] = (__bf16)v1.x; w[5] = (__bf16)v1.y; w[6] = (__bf16)v1.z; w[7] = (__bf16)v1.w;
        *reinterpret_cast<bf16x8*>(&As[arow * 32 + aq * 8]) = w;
    }
    __syncthreads();

    // ---- 16 planes, 2-phase pipeline: stage p+1 BEFORE MFMAs of p ----
    #pragma unroll
    for (int p = 0; p < 16; ++p) {
        const int cur = p & 1;
        if (p < 15) {
            const int nxt = cur ^ 1;
            const __bf16* src = w1s + (p + 1) * 16384 + tid * 8;
            __bf16* dst = Bs + nxt * 16384 + tid * 8;
            #pragma unroll
            for (int c = 0; c < 8; ++c)
                gl_lds16(src + c * 2048, dst + c * 2048);
            const float4* s = reinterpret_cast<const float4*>(agp + (p + 1) * 32);
            float4 v0 = s[0], v1 = s[1];
            bf16x8 w;
            w[0] = (__bf16)v0.x; w[1] = (__bf16)v0.y; w[2] = (__bf16)v0.z; w[3] = (__bf16)v0.w;
            w[4] = (__bf16)v1.x; w[5] = (__bf16)v1.y; w[6] = (__bf16)v1.z; w[7] = (__bf16)v1.w;
            *reinterpret_cast<bf16x8*>(&As[nxt * 2048 + arow * 32 + aq * 8]) = w;
        }
        const __bf16* Ap = As + cur * 2048;
        const __bf16* Bp = Bs + cur * 16384;
        bf16x8 af[4], bfr[8];
        #pragma unroll
        for (int mt = 0; mt < 4; ++mt)
            af[mt] = *reinterpret_cast<const bf16x8*>(
                &Ap[(mt * 16 + l16) * 32 + quad * 8]);
        #pragma unroll
        for (int nt = 0; nt < 8; ++nt)
            bfr[nt] = *reinterpret_cast<const bf16x8*>(
                &Bp[(wn * 128 + nt * 16 + l16) * 32 + quad * 8]);
        #pragma unroll
        for (int mt = 0; mt < 4; ++mt)
            #pragma unroll
            for (int nt = 0; nt < 8; ++nt)
                acc[mt][nt] = __builtin_amdgcn_mfma_f32_16x16x32_bf16(
                    af[mt], bfr[nt], acc[mt][nt], 0, 0, 0);
        __syncthreads();
    }

    // ---- epilogue: tanh(f_proj + hp) . Vw, reduce over u ----
    float hpv[8], vwv[8];
    #pragma unroll
    for (int nt = 0; nt < 8; ++nt) {
        int u = wn * 128 + nt * 16 + l16;       // C/D col = lane&15
        hpv[nt] = hp[b * U_DIM + u];
        vwv[nt] = Vw[u];
    }
    #pragma unroll
    for (int mt = 0; mt < 4; ++mt) {
        #pragma unroll
        for (int reg = 0; reg < 4; ++reg) {
            float s = 0.0f;
            #pragma unroll
            for (int nt = 0; nt < 8; ++nt) {
                float x = acc[mt][nt][reg] + hpv[nt];
                float e = exp2f(x * 2.88539008f);           // e^{2x}
                float th = 1.0f - 2.0f * __builtin_amdgcn_rcpf(e + 1.0f);
                s = fmaf(th, vwv[nt], s);
            }
            s += __shfl_xor(s, 1);
            s += __shfl_xor(s, 2);
            s += __shfl_xor(s, 4);
            s += __shfl_xor(s, 8);
            if (l16 == 0)
                red[wn * 64 + mt * 16 + quad * 4 + reg] = s;  // C/D row = quad*4+reg
        }
    }
    __syncthreads();

    // ---- chunk-local softmax partial: m_c, l_c, e_t in LDS ----
    if (tid < 64) {
        float s = red[tid] + red[64 + tid] + red[128 + tid] + red[192 + tid];
        float m = s;
        #pragma unroll
        for (int off = 1; off < 64; off <<= 1) m = fmaxf(m, __shfl_xor(m, off));
        float e = exp2f((s - m) * 1.44269504f);
        se[tid] = e;
        float l = e;
        #pragma unroll
        for (int off = 1; off < 64; off <<= 1) l += __shfl_xor(l, off);
        if (tid == 0) { mv[chunk] = m; lv[chunk] = l; }
    }
    __syncthreads();

    // ---- chunk context partial: ctx_c[d] = sum_t e_t * features[t][d] ----
    // rows row0..row0+63 were just streamed -> L2/L3 hot. 2 t-halves/thread.
    {
        const int col  = tid & 127;            // float4 column 0..127
        const int half = tid >> 7;             // 0..1
        const float4* fb = reinterpret_cast<const float4*>(features)
                           + (size_t)row0 * 128 + col;
        float4 a4 = {0.f, 0.f, 0.f, 0.f};
        #pragma unroll 8
        for (int i = 0; i < 32; ++i) {
            int t = half * 32 + i;
            float e = se[t];
            float4 v = fb[(size_t)t * 128];
            a4.x = fmaf(e, v.x, a4.x);
            a4.y = fmaf(e, v.y, a4.y);
            a4.z = fmaf(e, v.z, a4.z);
            a4.w = fmaf(e, v.w, a4.w);
        }
        red4[tid] = a4;
        __syncthreads();
        if (half == 0) {
            float4 v = red4[tid + 128];
            a4 = red4[tid];
            a4.x += v.x; a4.y += v.y; a4.z += v.z; a4.w += v.w;
            reinterpret_cast<float4*>(ctx)[(size_t)chunk * 128 + col] = a4;
        }
    }
}

// ---------------------------------------------------------------------------
// combine: per batch b, merge 32 chunk partials.
// M = max m_c; L = sum l_c e^{m_c-M}; out[d] = sum_c ctx_c[d] e^{m_c-M} / L.
// Grid 64, block 256. Reads 4 MB total.
// ---------------------------------------------------------------------------
__global__ void combine_kernel(const float* __restrict__ ctx,
                               const float* __restrict__ mv,
                               const float* __restrict__ lv,
                               float* __restrict__ out) {
    __shared__ float w[32];
    const int b   = blockIdx.x;
    const int tid = threadIdx.x;
    if (tid < 32) {
        float m = mv[b * 32 + tid];
        float M = m;
        #pragma unroll
        for (int off = 1; off < 32; off <<= 1) M = fmaxf(M, __shfl_xor(M, off));
        float wc = exp2f((m - M) * 1.44269504f);
        float l  = lv[b * 32 + tid] * wc;
        #pragma unroll
        for (int off = 1; off < 32; off <<= 1) l += __shfl_xor(l, off);
        w[tid] = wc / l;
    }
    __syncthreads();
    #pragma unroll
    for (int r = 0; r < 2; ++r) {
        int d = r * 256 + tid;
        float s = 0.0f;
        #pragma unroll
        for (int c = 0; c < 32; ++c)
            s = fmaf(ctx[(size_t)(b * 32 + c) * 512 + d], w[c], s);
        out[b * 512 + d] = s;
    }
}

// ---------------------------------------------------------------------------
extern "C" void kernel_launch(void* const* d_in, const int* in_sizes, int n_in,
                              void* d_out, int out_size, void* d_ws, size_t ws_size,
                              hipStream_t stream) {
    const float* features = (const float*)d_in[0];
    const float* hidden   = (const float*)d_in[1];
    const float* W1w      = (const float*)d_in[2];
    const float* W1b      = (const float*)d_in[3];
    const float* W2w      = (const float*)d_in[4];
    const float* W2b      = (const float*)d_in[5];
    const float* Vw       = (const float*)d_in[6];
    // V_b cancels in softmax — unused.

    char* ws = (char*)d_ws;
    __bf16* w1s = (__bf16*)ws;                         // 512 KiB
    float*  hp  = (float*)(ws + (512u << 10));         // 128 KiB
    float*  ctx = (float*)(ws + (640u << 10));         // 4 MiB
    float*  mv  = (float*)(ws + (640u << 10) + (4u << 20));          // 8 KiB
    float*  lv  = (float*)(ws + (640u << 10) + (4u << 20) + 8192u);  // 8 KiB

    hipLaunchKernelGGL(w1s_kernel, dim3(16, 8), dim3(256), 0, stream, W1w, w1s);
    hipLaunchKernelGGL(hproj_kernel, dim3(B_DIM, 2), dim3(256), 0, stream,
                       hidden, W2w, W2b, W1b, hp);
    hipLaunchKernelGGL(score_ctx_kernel, dim3(2048), dim3(256), 0, stream,
                       features, w1s, hp, Vw, ctx, mv, lv);
    hipLaunchKernelGGL(combine_kernel, dim3(B_DIM), dim3(256), 0, stream,
                       ctx, mv, lv, (float*)d_out);
}

// Round 3
// 469.194 us; speedup vs baseline: 1.0957x; 1.0140x over previous
//
#include <hip/hip_runtime.h>
#include <hip/hip_bf16.h>

#define B_DIM 64
#define T_DIM 2048
#define D_DIM 512
#define U_DIM 512

typedef __bf16 bf16x8 __attribute__((ext_vector_type(8)));
typedef float  f32x4  __attribute__((ext_vector_type(4)));
typedef unsigned int u32;

// async global->LDS, 16B per lane (global_load_lds_dwordx4)
__device__ __forceinline__ void gl_lds16(const __bf16* g, __bf16* l) {
    __builtin_amdgcn_global_load_lds(
        (const __attribute__((address_space(1))) u32*)g,
        (__attribute__((address_space(3))) u32*)l,
        16, 0, 0);
}

// ---------------------------------------------------------------------------
// W1 [D][U] fp32 -> w1s bf16 in FRAGMENT-LINEAR layout:
//   plane kb2 = d>>5 (32-k slab), fragment g = u>>4 (16-u group),
//   lane = (k>>3)*16 + (u&15), elem j = k&7  (k = d&31)
//   offset = kb2*16384 + g*512 + lane*8 + j   (bf16 elements)
// A wave's ds_read_b128 of one fragment is then CONTIGUOUS 1 KiB -> zero
// bank conflicts. Grid (16,8), block 256. LDS tile transpose.
// ---------------------------------------------------------------------------
__global__ void w1s_kernel(const float* __restrict__ W1w, __bf16* __restrict__ w1s) {
    __shared__ float tile[64][33];
    const int tid = threadIdx.x;
    const int kb2 = blockIdx.x;          // 32-d block
    const int ub  = blockIdx.y;          // 64-u block
    #pragma unroll
    for (int i = 0; i < 8; ++i) {
        int k = i * 4 + (tid >> 6);                 // 0..31
        int u = tid & 63;
        tile[u][k] = W1w[(kb2 * 32 + k) * U_DIM + ub * 64 + u];
    }
    __syncthreads();
    int u_l = tid >> 2;                  // 0..63
    int kq  = tid & 3;                   // k-block: k = kq*8 + j
    bf16x8 w;
    #pragma unroll
    for (int j = 0; j < 8; ++j) w[j] = (__bf16)tile[u_l][kq * 8 + j];
    int g    = ub * 4 + (u_l >> 4);
    int lane = kq * 16 + (u_l & 15);
    *reinterpret_cast<bf16x8*>(&w1s[kb2 * 16384 + g * 512 + lane * 8]) = w;
}

// ---------------------------------------------------------------------------
// hp[b][u] = W1_b[u] + W2_b[u] + hidden[b,:] @ W2[:,u]. Grid (B,2), block 256.
// ---------------------------------------------------------------------------
__global__ void hproj_kernel(const float* __restrict__ hidden,
                             const float* __restrict__ W2w,
                             const float* __restrict__ W2b,
                             const float* __restrict__ W1b,
                             float* __restrict__ hp) {
    int b = blockIdx.x;
    int u = blockIdx.y * 256 + threadIdx.x;
    float acc = W2b[u] + W1b[u];
    const float* hrow = hidden + b * D_DIM;
    #pragma unroll 8
    for (int d = 0; d < D_DIM; ++d)
        acc = fmaf(hrow[d], W2w[d * U_DIM + u], acc);
    hp[b * U_DIM + u] = acc;
}

// ---------------------------------------------------------------------------
// FUSED: scores + chunk-local online softmax + unnormalized context partial.
// One block = 64 (b,t) rows. Phase A: GEMM tanh-score, 2-phase pipelined LDS
// (BK=32 planes, dbuf A+B), fragment-linear LDS (conflict-free b128), A
// global loads issued 2 planes early (T14). Phase B: chunk max/sum. Phase C:
// ctx_c[d] = sum_t e^{s_t-m_c} * features[t][d]  (rows are L2-hot).
// Grid 2048, block 256 (4 waves x 128 u). LDS ~75 KiB -> 2 blocks/CU.
// ---------------------------------------------------------------------------
__global__ __launch_bounds__(256, 2) void score_ctx_kernel(
        const float*  __restrict__ features,
        const __bf16* __restrict__ w1s,
        const float*  __restrict__ hp,
        const float*  __restrict__ Vw,
        float*        __restrict__ ctx,     // [2048][512]
        float*        __restrict__ mv,      // [2048]
        float*        __restrict__ lv) {    // [2048]
    __shared__ __align__(16) char smem[8192 + 65536 + 1024 + 256];
    __bf16* As  = (__bf16*)smem;                      // [2][64*32]   8 KiB
    __bf16* Bs  = (__bf16*)(smem + 8192);             // [2][512*32] 64 KiB
    float*  red = (float*)(smem + 8192 + 65536);      // 256 f32      1 KiB
    float*  se  = (float*)(smem + 8192 + 65536 + 1024); // 64 f32
    float4* red4 = (float4*)Bs;                       // phase-C alias (4 KiB)

    const int tid  = threadIdx.x;
    const int chunk = blockIdx.x;
    const int row0 = chunk * 64;               // flattened (b,t) base
    const int b    = row0 >> 11;

    const int wn   = tid >> 6;                 // wave 0..3 -> u window wn*128
    const int lane = tid & 63;
    const int l16  = lane & 15;
    const int quad = lane >> 4;

    f32x4 acc[4][8];
    #pragma unroll
    for (int i = 0; i < 4; ++i)
        #pragma unroll
        for (int j = 0; j < 8; ++j)
            acc[i][j] = (f32x4)0.0f;

    // staging thread mapping: 4 threads/row, 128B fp32 per 4-lane group
    const int arow = tid >> 2;
    const int aq   = tid & 3;
    const float* agp = features + (size_t)(row0 + arow) * D_DIM + aq * 8;
    // fragment-linear A write slot: frag = arow>>4, lane' = aq*16 + (arow&15)
    const int awoff = (arow >> 4) * 512 + aq * 128 + (arow & 15) * 8;

#define CVT_W(V0, V1, W)                                                      \
    W[0] = (__bf16)V0.x; W[1] = (__bf16)V0.y; W[2] = (__bf16)V0.z;            \
    W[3] = (__bf16)V0.w; W[4] = (__bf16)V1.x; W[5] = (__bf16)V1.y;            \
    W[6] = (__bf16)V1.z; W[7] = (__bf16)V1.w;

    float4 ar[2][2];
    // ---- prologue: stage B plane 0; A plane 0 write; A plane 1 loads ----
    {
        const __bf16* src = w1s + tid * 8;
        #pragma unroll
        for (int c = 0; c < 8; ++c)
            gl_lds16(src + c * 2048, Bs + c * 2048 + tid * 8);
        const float4* s0 = reinterpret_cast<const float4*>(agp);
        ar[0][0] = s0[0]; ar[0][1] = s0[1];
        bf16x8 w;
        CVT_W(ar[0][0], ar[0][1], w)
        *reinterpret_cast<bf16x8*>(&As[awoff]) = w;
        const float4* s1 = reinterpret_cast<const float4*>(agp + 32);
        ar[1][0] = s1[0]; ar[1][1] = s1[1];
    }
    __syncthreads();

    // ---- 16 planes, 2-phase pipeline, A loads issued 2 planes early ----
    #pragma unroll
    for (int p = 0; p < 16; ++p) {
        const int cur = p & 1;
        const int nxt = cur ^ 1;
        if (p < 15) {
            // B: async stage plane p+1
            const __bf16* src = w1s + (p + 1) * 16384 + tid * 8;
            __bf16* dst = Bs + nxt * 16384 + tid * 8;
            #pragma unroll
            for (int c = 0; c < 8; ++c)
                gl_lds16(src + c * 2048, dst + c * 2048);
            // A: write plane p+1 from regs loaded at plane p-1 (arrived)
            bf16x8 w;
            CVT_W(ar[nxt][0], ar[nxt][1], w)
            *reinterpret_cast<bf16x8*>(&As[nxt * 2048 + awoff]) = w;
        }
        if (p < 14) {
            // A: issue global loads for plane p+2 (overwrites ar[p&1],
            // whose data was written to LDS at plane p-1)
            const float4* s = reinterpret_cast<const float4*>(agp + (p + 2) * 32);
            ar[cur][0] = s[0]; ar[cur][1] = s[1];
        }
        // fragment reads: contiguous 1 KiB per wave -> conflict-free
        const __bf16* Ap = As + cur * 2048;
        const __bf16* Bp = Bs + cur * 16384;
        bf16x8 af[4], bfr[8];
        #pragma unroll
        for (int mt = 0; mt < 4; ++mt)
            af[mt] = *reinterpret_cast<const bf16x8*>(&Ap[mt * 512 + lane * 8]);
        #pragma unroll
        for (int nt = 0; nt < 8; ++nt)
            bfr[nt] = *reinterpret_cast<const bf16x8*>(
                &Bp[(wn * 8 + nt) * 512 + lane * 8]);
        #pragma unroll
        for (int mt = 0; mt < 4; ++mt)
            #pragma unroll
            for (int nt = 0; nt < 8; ++nt)
                acc[mt][nt] = __builtin_amdgcn_mfma_f32_16x16x32_bf16(
                    af[mt], bfr[nt], acc[mt][nt], 0, 0, 0);
        __syncthreads();
    }
#undef CVT_W

    // ---- epilogue: tanh(f_proj + hp) . Vw, reduce over u ----
    float hpv[8], vwv[8];
    #pragma unroll
    for (int nt = 0; nt < 8; ++nt) {
        int u = wn * 128 + nt * 16 + l16;       // C/D col = lane&15
        hpv[nt] = hp[b * U_DIM + u];
        vwv[nt] = Vw[u];
    }
    #pragma unroll
    for (int mt = 0; mt < 4; ++mt) {
        #pragma unroll
        for (int reg = 0; reg < 4; ++reg) {
            float s = 0.0f;
            #pragma unroll
            for (int nt = 0; nt < 8; ++nt) {
                float x = acc[mt][nt][reg] + hpv[nt];
                float e = exp2f(x * 2.88539008f);           // e^{2x}
                float th = 1.0f - 2.0f * __builtin_amdgcn_rcpf(e + 1.0f);
                s = fmaf(th, vwv[nt], s);
            }
            s += __shfl_xor(s, 1);
            s += __shfl_xor(s, 2);
            s += __shfl_xor(s, 4);
            s += __shfl_xor(s, 8);
            if (l16 == 0)
                red[wn * 64 + mt * 16 + quad * 4 + reg] = s;  // C/D row = quad*4+reg
        }
    }
    __syncthreads();

    // ---- chunk-local softmax partial: m_c, l_c, e_t in LDS ----
    if (tid < 64) {
        float s = red[tid] + red[64 + tid] + red[128 + tid] + red[192 + tid];
        float m = s;
        #pragma unroll
        for (int off = 1; off < 64; off <<= 1) m = fmaxf(m, __shfl_xor(m, off));
        float e = exp2f((s - m) * 1.44269504f);
        se[tid] = e;
        float l = e;
        #pragma unroll
        for (int off = 1; off < 64; off <<= 1) l += __shfl_xor(l, off);
        if (tid == 0) { mv[chunk] = m; lv[chunk] = l; }
    }
    __syncthreads();

    // ---- chunk context partial: ctx_c[d] = sum_t e_t * features[t][d] ----
    // rows row0..row0+63 were just streamed -> L2/L3 hot. 2 t-halves/thread.
    {
        const int col  = tid & 127;            // float4 column 0..127
        const int half = tid >> 7;             // 0..1
        const float4* fb = reinterpret_cast<const float4*>(features)
                           + (size_t)row0 * 128 + col;
        float4 a4 = {0.f, 0.f, 0.f, 0.f};
        #pragma unroll 8
        for (int i = 0; i < 32; ++i) {
            int t = half * 32 + i;
            float e = se[t];
            float4 v = fb[(size_t)t * 128];
            a4.x = fmaf(e, v.x, a4.x);
            a4.y = fmaf(e, v.y, a4.y);
            a4.z = fmaf(e, v.z, a4.z);
            a4.w = fmaf(e, v.w, a4.w);
        }
        red4[tid] = a4;
        __syncthreads();
        if (half == 0) {
            float4 v = red4[tid + 128];
            a4 = red4[tid];
            a4.x += v.x; a4.y += v.y; a4.z += v.z; a4.w += v.w;
            reinterpret_cast<float4*>(ctx)[(size_t)chunk * 128 + col] = a4;
        }
    }
}

// ---------------------------------------------------------------------------
// combine: per batch b, merge 32 chunk partials.
// M = max m_c; L = sum l_c e^{m_c-M}; out[d] = sum_c ctx_c[d] e^{m_c-M} / L.
// Grid 64, block 256. Reads 4 MB total.
// ---------------------------------------------------------------------------
__global__ void combine_kernel(const float* __restrict__ ctx,
                               const float* __restrict__ mv,
                               const float* __restrict__ lv,
                               float* __restrict__ out) {
    __shared__ float w[32];
    const int b   = blockIdx.x;
    const int tid = threadIdx.x;
    if (tid < 32) {
        float m = mv[b * 32 + tid];
        float M = m;
        #pragma unroll
        for (int off = 1; off < 32; off <<= 1) M = fmaxf(M, __shfl_xor(M, off));
        float wc = exp2f((m - M) * 1.44269504f);
        float l  = lv[b * 32 + tid] * wc;
        #pragma unroll
        for (int off = 1; off < 32; off <<= 1) l += __shfl_xor(l, off);
        w[tid] = wc / l;
    }
    __syncthreads();
    #pragma unroll
    for (int r = 0; r < 2; ++r) {
        int d = r * 256 + tid;
        float s = 0.0f;
        #pragma unroll
        for (int c = 0; c < 32; ++c)
            s = fmaf(ctx[(size_t)(b * 32 + c) * 512 + d], w[c], s);
        out[b * 512 + d] = s;
    }
}

// ---------------------------------------------------------------------------
extern "C" void kernel_launch(void* const* d_in, const int* in_sizes, int n_in,
                              void* d_out, int out_size, void* d_ws, size_t ws_size,
                              hipStream_t stream) {
    const float* features = (const float*)d_in[0];
    const float* hidden   = (const float*)d_in[1];
    const float* W1w      = (const float*)d_in[2];
    const float* W1b      = (const float*)d_in[3];
    const float* W2w      = (const float*)d_in[4];
    const float* W2b      = (const float*)d_in[5];
    const float* Vw       = (const float*)d_in[6];
    // V_b cancels in softmax — unused.

    char* ws = (char*)d_ws;
    __bf16* w1s = (__bf16*)ws;                         // 512 KiB
    float*  hp  = (float*)(ws + (512u << 10));         // 128 KiB
    float*  ctx = (float*)(ws + (640u << 10));         // 4 MiB
    float*  mv  = (float*)(ws + (640u << 10) + (4u << 20));          // 8 KiB
    float*  lv  = (float*)(ws + (640u << 10) + (4u << 20) + 8192u);  // 8 KiB

    hipLaunchKernelGGL(w1s_kernel, dim3(16, 8), dim3(256), 0, stream, W1w, w1s);
    hipLaunchKernelGGL(hproj_kernel, dim3(B_DIM, 2), dim3(256), 0, stream,
                       hidden, W2w, W2b, W1b, hp);
    hipLaunchKernelGGL(score_ctx_kernel, dim3(2048), dim3(256), 0, stream,
                       features, w1s, hp, Vw, ctx, mv, lv);
    hipLaunchKernelGGL(combine_kernel, dim3(B_DIM), dim3(256), 0, stream,
                       ctx, mv, lv, (float*)d_out);
}